// Round 10
// baseline (400.223 us; speedup 1.0000x reference)
//
#include <hip/hip_runtime.h>
#include <math.h>

#define NN 100000
#define NE 1600000
#define ET (NE + NN)
#define SCAN_BLK 4096          // elements per scan1 block

typedef __attribute__((ext_vector_type(8))) short bf16x8;
typedef __attribute__((ext_vector_type(4))) float f32x4;

__device__ inline unsigned short f2bf(float f) {            // RNE float->bf16
  union { float f; unsigned u; } v; v.f = f;
  unsigned r = v.u + 0x7fffu + ((v.u >> 16) & 1u);
  return (unsigned short)(r >> 16);
}
__device__ inline float bflo(unsigned u) { union { unsigned u; float f; } v; v.u = u << 16; return v.f; }
__device__ inline float bfhi(unsigned u) { union { unsigned u; float f; } v; v.u = u & 0xffff0000u; return v.f; }

// ---------------- CSR build ----------------
// 16 edges per thread (block-strided) -> 16 independent atomics in flight
__global__ __launch_bounds__(256) void k_hist(const int* __restrict__ dst, int* __restrict__ counts,
                                              int* __restrict__ slots) {
  int base = blockIdx.x * 4096 + threadIdx.x;
#pragma unroll
  for (int j = 0; j < 16; ++j) {
    int i = base + j * 256;
    if (i < ET) {
      int d = (i < NE) ? dst[i] : (i - NE);
      slots[i] = atomicAdd(&counts[d], 1);
    }
  }
}

__global__ __launch_bounds__(256) void k_scan1(const int* __restrict__ counts, int* __restrict__ partial,
                                               int* __restrict__ blksum) {
  __shared__ int lds[256];
  int b = blockIdx.x, t = threadIdx.x;
  int base = b * SCAN_BLK + t * 16;
  int v[16];
  int s = 0;
#pragma unroll
  for (int j = 0; j < 16; j++) {
    int x = (base + j < NN) ? counts[base + j] : 0;
    s += x; v[j] = s;                                  // inclusive within thread
  }
  lds[t] = s; __syncthreads();
  int tot = s;
  for (int off = 1; off < 256; off <<= 1) {
    int u = 0; if (t >= off) u = lds[t - off];
    __syncthreads(); lds[t] += u; __syncthreads();
  }
  int pre = lds[t] - tot;
#pragma unroll
  for (int j = 0; j < 16; j++) if (base + j < NN) partial[base + j] = pre + v[j];
  if (t == 255) blksum[b] = lds[255];
}

__global__ __launch_bounds__(256) void k_scan2(int* __restrict__ blksum, int nb) {
  __shared__ int lds[256];
  int t = threadIdx.x;
  int v = (t < nb) ? blksum[t] : 0;
  lds[t] = v; __syncthreads();
  for (int off = 1; off < 256; off <<= 1) {
    int u = 0; if (t >= off) u = lds[t - off];
    __syncthreads(); lds[t] += u; __syncthreads();
  }
  if (t < nb) blksum[t] = lds[t] - v;   // exclusive block offsets
}

__global__ __launch_bounds__(256) void k_scan3(const int* __restrict__ partial, const int* __restrict__ blksum,
                                               int* __restrict__ rowptr) {
  int i = blockIdx.x * 256 + threadIdx.x;
  if (i >= NN) return;
  rowptr[i + 1] = partial[i] + blksum[i / SCAN_BLK];
  if (i == 0) rowptr[0] = 0;
}

__global__ __launch_bounds__(256) void k_scatter(const int* __restrict__ src, const int* __restrict__ dst,
                                                 const int* __restrict__ rowptr, const int* __restrict__ slots,
                                                 int* __restrict__ esrc) {
  int base = blockIdx.x * 4096 + threadIdx.x;
#pragma unroll
  for (int j = 0; j < 16; ++j) {
    int i = base + j * 256;
    if (i < ET) {
      int d, s;
      if (i < NE) { d = dst[i]; s = src[i]; } else { d = i - NE; s = d; }
      esrc[rowptr[d] + slots[i]] = s;
    }
  }
}

// ---------------- MFMA bf16 GEMM (h = X @ W) + fused alpha epilogue (layer 1) ----------------
template<int M, bool XBF>
__global__ __launch_bounds__(256) void k_gemm(const float* __restrict__ Xf, const unsigned short* __restrict__ Xb,
                                              const float* __restrict__ W,
                                              const float* __restrict__ a_src, const float* __restrict__ a_dst,
                                              unsigned short* __restrict__ Hf, float* __restrict__ as_, float* __restrict__ ad_) {
  constexpr int NCBW = M / 64;
  __shared__ __attribute__((aligned(16))) unsigned short xs[64 * 136];   // X tile / reused as h tile
  __shared__ __attribute__((aligned(16))) unsigned short wt[M * 136];    // W^T bf16: wt[col][k]
  __shared__ float asl[M], adl[M];
  const int t = threadIdx.x;
  const int wave = t >> 6, l = t & 63;
  const int lr = l & 15, kg = l >> 4;
  const int wc0 = wave * (M / 4);
  const int row0 = blockIdx.x * 64;

  if constexpr (XBF) {
#pragma unroll
    for (int p = 0; p < 4; ++p) {
      int f = p * 256 + t;
      int row = f >> 4, ch = f & 15;
      uint4 v = make_uint4(0, 0, 0, 0);
      if (row0 + row < NN) v = *(const uint4*)(Xb + (size_t)(row0 + row) * 128 + ch * 8);
      *(uint4*)(xs + row * 136 + ch * 8) = v;
    }
  } else {
#pragma unroll
    for (int p = 0; p < 8; ++p) {
      int f = p * 256 + t;
      int row = f >> 5, ch = f & 31;
      float4 v = make_float4(0.f, 0.f, 0.f, 0.f);
      if (row0 + row < NN) v = *(const float4*)(Xf + (size_t)(row0 + row) * 128 + ch * 4);
      uint2 pk;
      pk.x = (unsigned)f2bf(v.x) | ((unsigned)f2bf(v.y) << 16);
      pk.y = (unsigned)f2bf(v.z) | ((unsigned)f2bf(v.w) << 16);
      *(uint2*)(xs + row * 136 + ch * 4) = pk;
    }
  }
#pragma unroll
  for (int p = 0; p < M / 8; ++p) {
    int f = p * 256 + t;
    int k = f & 127, cg = f >> 7;
    float4 v = *(const float4*)(W + (size_t)k * M + cg * 4);
    wt[(cg * 4 + 0) * 136 + k] = f2bf(v.x);
    wt[(cg * 4 + 1) * 136 + k] = f2bf(v.y);
    wt[(cg * 4 + 2) * 136 + k] = f2bf(v.z);
    wt[(cg * 4 + 3) * 136 + k] = f2bf(v.w);
  }
  if (t < M) { asl[t] = a_src[t]; adl[t] = a_dst[t]; }
  __syncthreads();

  f32x4 acc[4][NCBW];
#pragma unroll
  for (int rb = 0; rb < 4; ++rb)
#pragma unroll
    for (int cb = 0; cb < NCBW; ++cb) acc[rb][cb] = (f32x4){0.f, 0.f, 0.f, 0.f};
#pragma unroll
  for (int kb = 0; kb < 4; ++kb) {
    bf16x8 af[4], bfr[NCBW];
#pragma unroll
    for (int rb = 0; rb < 4; ++rb)
      af[rb] = *(const bf16x8*)(xs + (rb * 16 + lr) * 136 + kb * 32 + kg * 8);
#pragma unroll
    for (int cb = 0; cb < NCBW; ++cb)
      bfr[cb] = *(const bf16x8*)(wt + (size_t)(wc0 + cb * 16 + lr) * 136 + kb * 32 + kg * 8);
#pragma unroll
    for (int rb = 0; rb < 4; ++rb)
#pragma unroll
      for (int cb = 0; cb < NCBW; ++cb)
        acc[rb][cb] = __builtin_amdgcn_mfma_f32_16x16x32_bf16(af[rb], bfr[cb], acc[rb][cb], 0, 0, 0);
  }

  __syncthreads();
#pragma unroll
  for (int rb = 0; rb < 4; ++rb)
#pragma unroll
    for (int cb = 0; cb < NCBW; ++cb)
#pragma unroll
      for (int r = 0; r < 4; ++r) {
        int row = rb * 16 + kg * 4 + r;
        int col = wc0 + cb * 16 + lr;
        xs[row * 136 + col] = f2bf(acc[rb][cb][r]);
      }
  __syncthreads();

  if constexpr (M == 128) {
    int row = t >> 2, cg = t & 3;
    int gr = row0 + row;
    if (gr < NN) {
#pragma unroll
      for (int j = 0; j < 4; ++j)
        *(uint4*)(Hf + (size_t)gr * 128 + cg * 32 + j * 8) = *(const uint4*)(xs + row * 136 + cg * 32 + j * 8);
#pragma unroll
      for (int hi = 0; hi < 2; ++hi) {
        int hh = cg * 2 + hi;
        uint4 u0 = *(const uint4*)(xs + row * 136 + hh * 16);
        uint4 u1 = *(const uint4*)(xs + row * 136 + hh * 16 + 8);
        float hv[16] = {bflo(u0.x), bfhi(u0.x), bflo(u0.y), bfhi(u0.y),
                        bflo(u0.z), bfhi(u0.z), bflo(u0.w), bfhi(u0.w),
                        bflo(u1.x), bfhi(u1.x), bflo(u1.y), bfhi(u1.y),
                        bflo(u1.z), bfhi(u1.z), bflo(u1.w), bfhi(u1.w)};
        float s1 = 0.f, s2 = 0.f;
#pragma unroll
        for (int j = 0; j < 16; ++j) { s1 += hv[j] * asl[hh * 16 + j]; s2 += hv[j] * adl[hh * 16 + j]; }
        as_[(size_t)gr * 8 + hh] = s1;
        ad_[(size_t)gr * 8 + hh] = s2;
      }
    }
  } else {
    int row = t >> 2, q = t & 3;
    int gr = row0 + row;
    uint4 u0 = *(const uint4*)(xs + row * 136 + q * 16);
    uint4 u1 = *(const uint4*)(xs + row * 136 + q * 16 + 8);
    float hv[16] = {bflo(u0.x), bfhi(u0.x), bflo(u0.y), bfhi(u0.y),
                    bflo(u0.z), bfhi(u0.z), bflo(u0.w), bfhi(u0.w),
                    bflo(u1.x), bfhi(u1.x), bflo(u1.y), bfhi(u1.y),
                    bflo(u1.z), bfhi(u1.z), bflo(u1.w), bfhi(u1.w)};
    float s1 = 0.f, s2 = 0.f;
#pragma unroll
    for (int j = 0; j < 16; ++j) { s1 += hv[j] * asl[q * 16 + j]; s2 += hv[j] * adl[q * 16 + j]; }
    s1 += __shfl_xor(s1, 1); s1 += __shfl_xor(s1, 2);
    s2 += __shfl_xor(s2, 1); s2 += __shfl_xor(s2, 2);
    if (gr < NN) {
      *(uint4*)(Hf + (size_t)gr * 64 + q * 16)     = u0;
      *(uint4*)(Hf + (size_t)gr * 64 + q * 16 + 8) = u1;
      if (q == 0) { as_[gr] = s1; ad_[gr] = s2; }
    }
  }
}

// ---------------- FUSED: aggregate layer l (8 heads x 16) -> LDS X-tile -> MFMA GEMM layer l+1 ----
// Block = 64 nodes. Phase 1: 1024 (node,oct) jobs aggregate straight into xs (bf16).
// Phase 2: MFMA with W^T staged in two K-halves (LDS ~37 KB -> 4 blocks/CU).
template<int M>
__global__ __launch_bounds__(256) void k_aggemm(
    const unsigned short* __restrict__ HfIn, const float* __restrict__ asIn, const float* __restrict__ adIn,
    const int* __restrict__ rowptr, const int* __restrict__ esrc, const float* __restrict__ bias,
    const float* __restrict__ W, const float* __restrict__ a_src, const float* __restrict__ a_dst,
    unsigned short* __restrict__ HfOut, float* __restrict__ asOut, float* __restrict__ adOut) {
  constexpr int NCBW = M / 64;
  __shared__ __attribute__((aligned(16))) unsigned short xs[64 * 136];   // aggregate out / h tile
  __shared__ __attribute__((aligned(16))) unsigned short wt[M * 72];     // W^T bf16, one K-half
  __shared__ float asl[M], adl[M];
  const int t = threadIdx.x;
  const int wave = t >> 6, l = t & 63;
  const int lr = l & 15, kg = l >> 4;
  const int wc0 = wave * (M / 4);
  const int row0 = blockIdx.x * 64;

  // stage W^T K-half 0 (k = 0..63)
  {
    constexpr int PT = (M * 64 / 4) / 256;
#pragma unroll
    for (int p = 0; p < PT; ++p) {
      int f = p * 256 + t;
      int k = f / (M / 4), cg = f % (M / 4);
      float4 v = *(const float4*)(W + (size_t)k * M + cg * 4);
      wt[(cg * 4 + 0) * 72 + k] = f2bf(v.x);
      wt[(cg * 4 + 1) * 72 + k] = f2bf(v.y);
      wt[(cg * 4 + 2) * 72 + k] = f2bf(v.z);
      wt[(cg * 4 + 3) * 72 + k] = f2bf(v.w);
    }
  }
  if (t < M) { asl[t] = a_src[t]; adl[t] = a_dst[t]; }

  // phase 1: aggregate (inline exp, 2-way ILP) -> xs
#pragma unroll
  for (int jj = 0; jj < 4; ++jj) {
    int j = jj * 256 + t;
    int nl = j >> 4, q = j & 15;
    int node = row0 + nl;
    int c = q * 8, hh = q >> 1;
    float o[8];
    if (node < NN) {
      int i0 = rowptr[node], i1 = rowptr[node + 1];
      float ad = adIn[node * 8 + hh];
      float d0 = 0.f, d1 = 0.f;
      float a0[8] = {}, a1[8] = {};
      int i = i0;
      for (; i + 1 < i1; i += 2) {
        int sA = esrc[i], sB = esrc[i + 1];
        float eA = asIn[sA * 8 + hh] + ad;
        float eB = asIn[sB * 8 + hh] + ad;
        uint4 hA = *(const uint4*)(HfIn + (size_t)sA * 128 + c);
        uint4 hB = *(const uint4*)(HfIn + (size_t)sB * 128 + c);
        eA = fmaxf(eA, 0.2f * eA);
        eB = fmaxf(eB, 0.2f * eB);
        float pA = __expf(eA), pB = __expf(eB);
        d0 += pA;                             d1 += pB;
        a0[0] = fmaf(pA, bflo(hA.x), a0[0]);  a1[0] = fmaf(pB, bflo(hB.x), a1[0]);
        a0[1] = fmaf(pA, bfhi(hA.x), a0[1]);  a1[1] = fmaf(pB, bfhi(hB.x), a1[1]);
        a0[2] = fmaf(pA, bflo(hA.y), a0[2]);  a1[2] = fmaf(pB, bflo(hB.y), a1[2]);
        a0[3] = fmaf(pA, bfhi(hA.y), a0[3]);  a1[3] = fmaf(pB, bfhi(hB.y), a1[3]);
        a0[4] = fmaf(pA, bflo(hA.z), a0[4]);  a1[4] = fmaf(pB, bflo(hB.z), a1[4]);
        a0[5] = fmaf(pA, bfhi(hA.z), a0[5]);  a1[5] = fmaf(pB, bfhi(hB.z), a1[5]);
        a0[6] = fmaf(pA, bflo(hA.w), a0[6]);  a1[6] = fmaf(pB, bflo(hB.w), a1[6]);
        a0[7] = fmaf(pA, bfhi(hA.w), a0[7]);  a1[7] = fmaf(pB, bfhi(hB.w), a1[7]);
      }
      if (i < i1) {
        int sA = esrc[i];
        float eA = asIn[sA * 8 + hh] + ad;
        uint4 hA = *(const uint4*)(HfIn + (size_t)sA * 128 + c);
        eA = fmaxf(eA, 0.2f * eA);
        float pA = __expf(eA);
        d0 += pA;
        a0[0] = fmaf(pA, bflo(hA.x), a0[0]);
        a0[1] = fmaf(pA, bfhi(hA.x), a0[1]);
        a0[2] = fmaf(pA, bflo(hA.y), a0[2]);
        a0[3] = fmaf(pA, bfhi(hA.y), a0[3]);
        a0[4] = fmaf(pA, bflo(hA.z), a0[4]);
        a0[5] = fmaf(pA, bfhi(hA.z), a0[5]);
        a0[6] = fmaf(pA, bflo(hA.w), a0[6]);
        a0[7] = fmaf(pA, bfhi(hA.w), a0[7]);
      }
      float inv = 1.f / (d0 + d1);
#pragma unroll
      for (int jx = 0; jx < 8; ++jx) {
        float v = (a0[jx] + a1[jx]) * inv + bias[c + jx];
        o[jx] = v > 0.f ? v : __expf(v) - 1.f;         // ELU
      }
    } else {
#pragma unroll
      for (int jx = 0; jx < 8; ++jx) o[jx] = 0.f;
    }
    uint4 pk;
    pk.x = (unsigned)f2bf(o[0]) | ((unsigned)f2bf(o[1]) << 16);
    pk.y = (unsigned)f2bf(o[2]) | ((unsigned)f2bf(o[3]) << 16);
    pk.z = (unsigned)f2bf(o[4]) | ((unsigned)f2bf(o[5]) << 16);
    pk.w = (unsigned)f2bf(o[6]) | ((unsigned)f2bf(o[7]) << 16);
    *(uint4*)(xs + nl * 136 + c) = pk;
  }
  __syncthreads();

  // phase 2: MFMA, K-halves
  f32x4 acc[4][NCBW];
#pragma unroll
  for (int rb = 0; rb < 4; ++rb)
#pragma unroll
    for (int cb = 0; cb < NCBW; ++cb) acc[rb][cb] = (f32x4){0.f, 0.f, 0.f, 0.f};
#pragma unroll
  for (int kb = 0; kb < 2; ++kb) {
    bf16x8 af[4], bfr[NCBW];
#pragma unroll
    for (int rb = 0; rb < 4; ++rb)
      af[rb] = *(const bf16x8*)(xs + (rb * 16 + lr) * 136 + kb * 32 + kg * 8);
#pragma unroll
    for (int cb = 0; cb < NCBW; ++cb)
      bfr[cb] = *(const bf16x8*)(wt + (size_t)(wc0 + cb * 16 + lr) * 72 + kb * 32 + kg * 8);
#pragma unroll
    for (int rb = 0; rb < 4; ++rb)
#pragma unroll
      for (int cb = 0; cb < NCBW; ++cb)
        acc[rb][cb] = __builtin_amdgcn_mfma_f32_16x16x32_bf16(af[rb], bfr[cb], acc[rb][cb], 0, 0, 0);
  }
  __syncthreads();
  // restage W^T K-half 1 (k = 64..127)
  {
    constexpr int PT = (M * 64 / 4) / 256;
#pragma unroll
    for (int p = 0; p < PT; ++p) {
      int f = p * 256 + t;
      int k = f / (M / 4), cg = f % (M / 4);
      float4 v = *(const float4*)(W + (size_t)(k + 64) * M + cg * 4);
      wt[(cg * 4 + 0) * 72 + k] = f2bf(v.x);
      wt[(cg * 4 + 1) * 72 + k] = f2bf(v.y);
      wt[(cg * 4 + 2) * 72 + k] = f2bf(v.z);
      wt[(cg * 4 + 3) * 72 + k] = f2bf(v.w);
    }
  }
  __syncthreads();
#pragma unroll
  for (int kb = 0; kb < 2; ++kb) {
    bf16x8 af[4], bfr[NCBW];
#pragma unroll
    for (int rb = 0; rb < 4; ++rb)
      af[rb] = *(const bf16x8*)(xs + (rb * 16 + lr) * 136 + (kb + 2) * 32 + kg * 8);
#pragma unroll
    for (int cb = 0; cb < NCBW; ++cb)
      bfr[cb] = *(const bf16x8*)(wt + (size_t)(wc0 + cb * 16 + lr) * 72 + kb * 32 + kg * 8);
#pragma unroll
    for (int rb = 0; rb < 4; ++rb)
#pragma unroll
      for (int cb = 0; cb < NCBW; ++cb)
        acc[rb][cb] = __builtin_amdgcn_mfma_f32_16x16x32_bf16(af[rb], bfr[cb], acc[rb][cb], 0, 0, 0);
  }
  __syncthreads();

  // epilogue: acc -> xs (bf16 h tile) -> coalesced global writes + alpha dots
#pragma unroll
  for (int rb = 0; rb < 4; ++rb)
#pragma unroll
    for (int cb = 0; cb < NCBW; ++cb)
#pragma unroll
      for (int r = 0; r < 4; ++r) {
        int row = rb * 16 + kg * 4 + r;
        int col = wc0 + cb * 16 + lr;
        xs[row * 136 + col] = f2bf(acc[rb][cb][r]);
      }
  __syncthreads();

  if constexpr (M == 128) {
    int row = t >> 2, cg = t & 3;
    int gr = row0 + row;
    if (gr < NN) {
#pragma unroll
      for (int j = 0; j < 4; ++j)
        *(uint4*)(HfOut + (size_t)gr * 128 + cg * 32 + j * 8) = *(const uint4*)(xs + row * 136 + cg * 32 + j * 8);
#pragma unroll
      for (int hi = 0; hi < 2; ++hi) {
        int hh = cg * 2 + hi;
        uint4 u0 = *(const uint4*)(xs + row * 136 + hh * 16);
        uint4 u1 = *(const uint4*)(xs + row * 136 + hh * 16 + 8);
        float hv[16] = {bflo(u0.x), bfhi(u0.x), bflo(u0.y), bfhi(u0.y),
                        bflo(u0.z), bfhi(u0.z), bflo(u0.w), bfhi(u0.w),
                        bflo(u1.x), bfhi(u1.x), bflo(u1.y), bfhi(u1.y),
                        bflo(u1.z), bfhi(u1.z), bflo(u1.w), bfhi(u1.w)};
        float s1 = 0.f, s2 = 0.f;
#pragma unroll
        for (int j = 0; j < 16; ++j) { s1 += hv[j] * asl[hh * 16 + j]; s2 += hv[j] * adl[hh * 16 + j]; }
        asOut[(size_t)gr * 8 + hh] = s1;
        adOut[(size_t)gr * 8 + hh] = s2;
      }
    }
  } else {
    int row = t >> 2, q = t & 3;
    int gr = row0 + row;
    uint4 u0 = *(const uint4*)(xs + row * 136 + q * 16);
    uint4 u1 = *(const uint4*)(xs + row * 136 + q * 16 + 8);
    float hv[16] = {bflo(u0.x), bfhi(u0.x), bflo(u0.y), bfhi(u0.y),
                    bflo(u0.z), bfhi(u0.z), bflo(u0.w), bfhi(u0.w),
                    bflo(u1.x), bfhi(u1.x), bflo(u1.y), bfhi(u1.y),
                    bflo(u1.z), bfhi(u1.z), bflo(u1.w), bfhi(u1.w)};
    float s1 = 0.f, s2 = 0.f;
#pragma unroll
    for (int j = 0; j < 16; ++j) { s1 += hv[j] * asl[q * 16 + j]; s2 += hv[j] * adl[q * 16 + j]; }
    s1 += __shfl_xor(s1, 1); s1 += __shfl_xor(s1, 2);
    s2 += __shfl_xor(s2, 1); s2 += __shfl_xor(s2, 2);
    if (gr < NN) {
      *(uint4*)(HfOut + (size_t)gr * 64 + q * 16)     = u0;
      *(uint4*)(HfOut + (size_t)gr * 64 + q * 16 + 8) = u1;
      if (q == 0) { asOut[gr] = s1; adOut[gr] = s2; }
    }
  }
}

// ---------------- final aggregation (1 head x 64) + fused 64->2 output linear ----------------
template<int HH, int C, bool FINAL>
__global__ __launch_bounds__(256) void k_aggregate(const unsigned short* __restrict__ Hf,
                                                   const float* __restrict__ as_, const float* __restrict__ ad_,
                                                   const int* __restrict__ rowptr, const int* __restrict__ esrc,
                                                   const float* __restrict__ bias,
                                                   const float* __restrict__ Wout, const float* __restrict__ bout,
                                                   unsigned short* __restrict__ outb, float* __restrict__ outf) {
  constexpr int CT = HH * C;
  constexpr int Q = CT / 8;
  int g = blockIdx.x * 256 + threadIdx.x;
  if (g >= NN * Q) return;
  int node = g / Q;
  int q = g - node * Q;
  int c = q * 8;
  int hh = c / C;
  int i0 = rowptr[node], i1 = rowptr[node + 1];
  float ad = ad_[node * HH + hh];
  float d0 = 0.f, d1 = 0.f;
  float a0[8] = {}, a1[8] = {};
  int i = i0;
  for (; i + 1 < i1; i += 2) {
    int sA = esrc[i], sB = esrc[i + 1];
    float eA = as_[sA * HH + hh] + ad;
    float eB = as_[sB * HH + hh] + ad;
    uint4 hA = *(const uint4*)(Hf + (size_t)sA * CT + c);
    uint4 hB = *(const uint4*)(Hf + (size_t)sB * CT + c);
    eA = fmaxf(eA, 0.2f * eA);
    eB = fmaxf(eB, 0.2f * eB);
    float pA = __expf(eA), pB = __expf(eB);
    d0 += pA;                             d1 += pB;
    a0[0] = fmaf(pA, bflo(hA.x), a0[0]);  a1[0] = fmaf(pB, bflo(hB.x), a1[0]);
    a0[1] = fmaf(pA, bfhi(hA.x), a0[1]);  a1[1] = fmaf(pB, bfhi(hB.x), a1[1]);
    a0[2] = fmaf(pA, bflo(hA.y), a0[2]);  a1[2] = fmaf(pB, bflo(hB.y), a1[2]);
    a0[3] = fmaf(pA, bfhi(hA.y), a0[3]);  a1[3] = fmaf(pB, bfhi(hB.y), a1[3]);
    a0[4] = fmaf(pA, bflo(hA.z), a0[4]);  a1[4] = fmaf(pB, bflo(hB.z), a1[4]);
    a0[5] = fmaf(pA, bfhi(hA.z), a0[5]);  a1[5] = fmaf(pB, bfhi(hB.z), a1[5]);
    a0[6] = fmaf(pA, bflo(hA.w), a0[6]);  a1[6] = fmaf(pB, bflo(hB.w), a1[6]);
    a0[7] = fmaf(pA, bfhi(hA.w), a0[7]);  a1[7] = fmaf(pB, bfhi(hB.w), a1[7]);
  }
  if (i < i1) {
    int sA = esrc[i];
    float eA = as_[sA * HH + hh] + ad;
    uint4 hA = *(const uint4*)(Hf + (size_t)sA * CT + c);
    eA = fmaxf(eA, 0.2f * eA);
    float pA = __expf(eA);
    d0 += pA;
    a0[0] = fmaf(pA, bflo(hA.x), a0[0]);
    a0[1] = fmaf(pA, bfhi(hA.x), a0[1]);
    a0[2] = fmaf(pA, bflo(hA.y), a0[2]);
    a0[3] = fmaf(pA, bfhi(hA.y), a0[3]);
    a0[4] = fmaf(pA, bflo(hA.z), a0[4]);
    a0[5] = fmaf(pA, bfhi(hA.z), a0[5]);
    a0[6] = fmaf(pA, bflo(hA.w), a0[6]);
    a0[7] = fmaf(pA, bfhi(hA.w), a0[7]);
  }
  float inv = 1.f / (d0 + d1);
  float o[8];
#pragma unroll
  for (int j = 0; j < 8; ++j) {
    float v = (a0[j] + a1[j]) * inv + bias[c + j];
    o[j] = v > 0.f ? v : __expf(v) - 1.f;              // ELU
  }
  if constexpr (!FINAL) {
    uint4 pk;
    pk.x = (unsigned)f2bf(o[0]) | ((unsigned)f2bf(o[1]) << 16);
    pk.y = (unsigned)f2bf(o[2]) | ((unsigned)f2bf(o[3]) << 16);
    pk.z = (unsigned)f2bf(o[4]) | ((unsigned)f2bf(o[5]) << 16);
    pk.w = (unsigned)f2bf(o[6]) | ((unsigned)f2bf(o[7]) << 16);
    *(uint4*)(outb + (size_t)node * CT + c) = pk;
  } else {
    float p0 = 0.f, p1 = 0.f;
#pragma unroll
    for (int j = 0; j < 8; ++j) { p0 += o[j] * Wout[(c + j) * 2 + 0]; p1 += o[j] * Wout[(c + j) * 2 + 1]; }
#pragma unroll
    for (int off = 1; off < 8; off <<= 1) { p0 += __shfl_xor(p0, off); p1 += __shfl_xor(p1, off); }
    if (q == 0) { outf[node * 2 + 0] = p0 + bout[0]; outf[node * 2 + 1] = p1 + bout[1]; }
  }
}

extern "C" void kernel_launch(void* const* d_in, const int* in_sizes, int n_in,
                              void* d_out, int out_size, void* d_ws, size_t ws_size,
                              hipStream_t stream) {
  const float* x    = (const float*)d_in[0];
  const int*   ei   = (const int*)d_in[1];
  const float* W1   = (const float*)d_in[2];
  const float* as1  = (const float*)d_in[3];
  const float* ad1  = (const float*)d_in[4];
  const float* b1   = (const float*)d_in[5];
  const float* W2   = (const float*)d_in[6];
  const float* as2  = (const float*)d_in[7];
  const float* ad2  = (const float*)d_in[8];
  const float* b2   = (const float*)d_in[9];
  const float* W3   = (const float*)d_in[10];
  const float* as3  = (const float*)d_in[11];
  const float* ad3  = (const float*)d_in[12];
  const float* b3   = (const float*)d_in[13];
  const float* Wout = (const float*)d_in[14];
  const float* bout = (const float*)d_in[15];
  const int* srcp = ei;
  const int* dstp = ei + NE;

  char* p = (char*)d_ws;
  auto alloc = [&](size_t bytes) { char* r = p; p += (bytes + 255) & ~size_t(255); return r; };
  int*            rowptr  = (int*)alloc((size_t)(NN + 1) * 4);
  int*            counts  = (int*)alloc((size_t)NN * 4);
  int*            partial = (int*)alloc((size_t)NN * 4);
  int*            blksum  = (int*)alloc(256 * 4);
  int*            esrc    = (int*)alloc((size_t)ET * 4);
  int*            slots   = (int*)alloc((size_t)ET * 4);
  float*          asbA    = (float*)alloc((size_t)NN * 8 * 4);
  float*          adbA    = (float*)alloc((size_t)NN * 8 * 4);
  float*          asbB    = (float*)alloc((size_t)NN * 8 * 4);
  float*          adbB    = (float*)alloc((size_t)NN * 8 * 4);
  unsigned short* hfA     = (unsigned short*)alloc((size_t)NN * 128 * 2);   // layer1 / layer3 h table
  unsigned short* hfB     = (unsigned short*)alloc((size_t)NN * 128 * 2);   // layer2 h table

  hipMemsetAsync(counts, 0, (size_t)NN * 4, stream);
  int gE16 = (ET + 4095) / 4096;
  int nb = (NN + SCAN_BLK - 1) / SCAN_BLK;
  k_hist<<<gE16, 256, 0, stream>>>(dstp, counts, slots);
  k_scan1<<<nb, 256, 0, stream>>>(counts, partial, blksum);
  k_scan2<<<1, 256, 0, stream>>>(blksum, nb);
  k_scan3<<<(NN + 255) / 256, 256, 0, stream>>>(partial, blksum, rowptr);
  k_scatter<<<gE16, 256, 0, stream>>>(srcp, dstp, rowptr, slots, esrc);

  int gGemm = (NN + 63) / 64;
  // layer 1 GEMM (fp32 x input)
  k_gemm<128, false><<<gGemm, 256, 0, stream>>>(x, nullptr, W1, as1, ad1, hfA, asbA, adbA);
  // aggregate layer1 + GEMM layer2 (fused)
  k_aggemm<128><<<gGemm, 256, 0, stream>>>(hfA, asbA, adbA, rowptr, esrc, b1, W2, as2, ad2, hfB, asbB, adbB);
  // aggregate layer2 + GEMM layer3 (fused)
  k_aggemm<64><<<gGemm, 256, 0, stream>>>(hfB, asbB, adbB, rowptr, esrc, b2, W3, as3, ad3, hfA, asbA, adbA);
  // aggregate layer3 + fused 64->2 output head
  k_aggregate<1, 64, true><<<(NN * 8 + 255) / 256, 256, 0, stream>>>(hfA, asbA, adbA, rowptr, esrc, b3, Wout, bout, nullptr, (float*)d_out);
}

// Round 11
// 386.000 us; speedup vs baseline: 1.0368x; 1.0368x over previous
//
#include <hip/hip_runtime.h>
#include <math.h>

#define NN 100000
#define NE 1600000
#define ET (NE + NN)
#define SCAN_BLK 4096          // elements per scan1 block

typedef __attribute__((ext_vector_type(8))) short bf16x8;
typedef __attribute__((ext_vector_type(4))) float f32x4;

__device__ inline unsigned short f2bf(float f) {            // RNE float->bf16
  union { float f; unsigned u; } v; v.f = f;
  unsigned r = v.u + 0x7fffu + ((v.u >> 16) & 1u);
  return (unsigned short)(r >> 16);
}
__device__ inline float bflo(unsigned u) { union { unsigned u; float f; } v; v.u = u << 16; return v.f; }
__device__ inline float bfhi(unsigned u) { union { unsigned u; float f; } v; v.u = u & 0xffff0000u; return v.f; }

// ---------------- CSR build ----------------
// 16 edges per thread (block-strided) -> 16 independent atomics in flight
__global__ __launch_bounds__(256) void k_hist(const int* __restrict__ dst, int* __restrict__ counts,
                                              int* __restrict__ slots) {
  int base = blockIdx.x * 4096 + threadIdx.x;
#pragma unroll
  for (int j = 0; j < 16; ++j) {
    int i = base + j * 256;
    if (i < ET) {
      int d = (i < NE) ? dst[i] : (i - NE);
      slots[i] = atomicAdd(&counts[d], 1);
    }
  }
}

__global__ __launch_bounds__(256) void k_scan1(const int* __restrict__ counts, int* __restrict__ partial,
                                               int* __restrict__ blksum) {
  __shared__ int lds[256];
  int b = blockIdx.x, t = threadIdx.x;
  int base = b * SCAN_BLK + t * 16;
  int v[16];
  int s = 0;
#pragma unroll
  for (int j = 0; j < 16; j++) {
    int x = (base + j < NN) ? counts[base + j] : 0;
    s += x; v[j] = s;                                  // inclusive within thread
  }
  lds[t] = s; __syncthreads();
  int tot = s;
  for (int off = 1; off < 256; off <<= 1) {
    int u = 0; if (t >= off) u = lds[t - off];
    __syncthreads(); lds[t] += u; __syncthreads();
  }
  int pre = lds[t] - tot;
#pragma unroll
  for (int j = 0; j < 16; j++) if (base + j < NN) partial[base + j] = pre + v[j];
  if (t == 255) blksum[b] = lds[255];
}

__global__ __launch_bounds__(256) void k_scan2(int* __restrict__ blksum, int nb) {
  __shared__ int lds[256];
  int t = threadIdx.x;
  int v = (t < nb) ? blksum[t] : 0;
  lds[t] = v; __syncthreads();
  for (int off = 1; off < 256; off <<= 1) {
    int u = 0; if (t >= off) u = lds[t - off];
    __syncthreads(); lds[t] += u; __syncthreads();
  }
  if (t < nb) blksum[t] = lds[t] - v;   // exclusive block offsets
}

__global__ __launch_bounds__(256) void k_scan3(const int* __restrict__ partial, const int* __restrict__ blksum,
                                               int* __restrict__ rowptr) {
  int i = blockIdx.x * 256 + threadIdx.x;
  if (i >= NN) return;
  rowptr[i + 1] = partial[i] + blksum[i / SCAN_BLK];
  if (i == 0) rowptr[0] = 0;
}

__global__ __launch_bounds__(256) void k_scatter(const int* __restrict__ src, const int* __restrict__ dst,
                                                 const int* __restrict__ rowptr, const int* __restrict__ slots,
                                                 int* __restrict__ esrc) {
  int base = blockIdx.x * 4096 + threadIdx.x;
#pragma unroll
  for (int j = 0; j < 16; ++j) {
    int i = base + j * 256;
    if (i < ET) {
      int d, s;
      if (i < NE) { d = dst[i]; s = src[i]; } else { d = i - NE; s = d; }
      esrc[rowptr[d] + slots[i]] = s;
    }
  }
}

// ---------------- MFMA bf16 GEMM (h = X @ W) + fused alpha epilogue ----------------
// X: NN x 128 (fp32 or bf16). W: 128 x M fp32 row-major -> bf16 transposed in LDS.
// Block: 64 rows x M cols, 256 threads = 4 waves; wave w covers cols [w*M/4, (w+1)*M/4).
template<int M, bool XBF>
__global__ __launch_bounds__(256) void k_gemm(const float* __restrict__ Xf, const unsigned short* __restrict__ Xb,
                                              const float* __restrict__ W,
                                              const float* __restrict__ a_src, const float* __restrict__ a_dst,
                                              unsigned short* __restrict__ Hf, float* __restrict__ as_, float* __restrict__ ad_) {
  constexpr int NCBW = M / 64;
  __shared__ __attribute__((aligned(16))) unsigned short xs[64 * 136];   // X tile / reused as h tile
  __shared__ __attribute__((aligned(16))) unsigned short wt[M * 136];    // W^T bf16: wt[col][k]
  __shared__ float asl[M], adl[M];
  const int t = threadIdx.x;
  const int wave = t >> 6, l = t & 63;
  const int lr = l & 15, kg = l >> 4;
  const int wc0 = wave * (M / 4);
  const int row0 = blockIdx.x * 64;

  if constexpr (XBF) {
#pragma unroll
    for (int p = 0; p < 4; ++p) {
      int f = p * 256 + t;
      int row = f >> 4, ch = f & 15;
      uint4 v = make_uint4(0, 0, 0, 0);
      if (row0 + row < NN) v = *(const uint4*)(Xb + (size_t)(row0 + row) * 128 + ch * 8);
      *(uint4*)(xs + row * 136 + ch * 8) = v;
    }
  } else {
#pragma unroll
    for (int p = 0; p < 8; ++p) {
      int f = p * 256 + t;
      int row = f >> 5, ch = f & 31;
      float4 v = make_float4(0.f, 0.f, 0.f, 0.f);
      if (row0 + row < NN) v = *(const float4*)(Xf + (size_t)(row0 + row) * 128 + ch * 4);
      uint2 pk;
      pk.x = (unsigned)f2bf(v.x) | ((unsigned)f2bf(v.y) << 16);
      pk.y = (unsigned)f2bf(v.z) | ((unsigned)f2bf(v.w) << 16);
      *(uint2*)(xs + row * 136 + ch * 4) = pk;
    }
  }
#pragma unroll
  for (int p = 0; p < M / 8; ++p) {
    int f = p * 256 + t;
    int k = f & 127, cg = f >> 7;
    float4 v = *(const float4*)(W + (size_t)k * M + cg * 4);
    wt[(cg * 4 + 0) * 136 + k] = f2bf(v.x);
    wt[(cg * 4 + 1) * 136 + k] = f2bf(v.y);
    wt[(cg * 4 + 2) * 136 + k] = f2bf(v.z);
    wt[(cg * 4 + 3) * 136 + k] = f2bf(v.w);
  }
  if (t < M) { asl[t] = a_src[t]; adl[t] = a_dst[t]; }
  __syncthreads();

  f32x4 acc[4][NCBW];
#pragma unroll
  for (int rb = 0; rb < 4; ++rb)
#pragma unroll
    for (int cb = 0; cb < NCBW; ++cb) acc[rb][cb] = (f32x4){0.f, 0.f, 0.f, 0.f};
#pragma unroll
  for (int kb = 0; kb < 4; ++kb) {
    bf16x8 af[4], bfr[NCBW];
#pragma unroll
    for (int rb = 0; rb < 4; ++rb)
      af[rb] = *(const bf16x8*)(xs + (rb * 16 + lr) * 136 + kb * 32 + kg * 8);
#pragma unroll
    for (int cb = 0; cb < NCBW; ++cb)
      bfr[cb] = *(const bf16x8*)(wt + (size_t)(wc0 + cb * 16 + lr) * 136 + kb * 32 + kg * 8);
#pragma unroll
    for (int rb = 0; rb < 4; ++rb)
#pragma unroll
      for (int cb = 0; cb < NCBW; ++cb)
        acc[rb][cb] = __builtin_amdgcn_mfma_f32_16x16x32_bf16(af[rb], bfr[cb], acc[rb][cb], 0, 0, 0);
  }

  __syncthreads();
#pragma unroll
  for (int rb = 0; rb < 4; ++rb)
#pragma unroll
    for (int cb = 0; cb < NCBW; ++cb)
#pragma unroll
      for (int r = 0; r < 4; ++r) {
        int row = rb * 16 + kg * 4 + r;
        int col = wc0 + cb * 16 + lr;
        xs[row * 136 + col] = f2bf(acc[rb][cb][r]);
      }
  __syncthreads();

  if constexpr (M == 128) {
    int row = t >> 2, cg = t & 3;
    int gr = row0 + row;
    if (gr < NN) {
#pragma unroll
      for (int j = 0; j < 4; ++j)
        *(uint4*)(Hf + (size_t)gr * 128 + cg * 32 + j * 8) = *(const uint4*)(xs + row * 136 + cg * 32 + j * 8);
#pragma unroll
      for (int hi = 0; hi < 2; ++hi) {
        int hh = cg * 2 + hi;
        uint4 u0 = *(const uint4*)(xs + row * 136 + hh * 16);
        uint4 u1 = *(const uint4*)(xs + row * 136 + hh * 16 + 8);
        float hv[16] = {bflo(u0.x), bfhi(u0.x), bflo(u0.y), bfhi(u0.y),
                        bflo(u0.z), bfhi(u0.z), bflo(u0.w), bfhi(u0.w),
                        bflo(u1.x), bfhi(u1.x), bflo(u1.y), bfhi(u1.y),
                        bflo(u1.z), bfhi(u1.z), bflo(u1.w), bfhi(u1.w)};
        float s1 = 0.f, s2 = 0.f;
#pragma unroll
        for (int j = 0; j < 16; ++j) { s1 += hv[j] * asl[hh * 16 + j]; s2 += hv[j] * adl[hh * 16 + j]; }
        as_[(size_t)gr * 8 + hh] = s1;
        ad_[(size_t)gr * 8 + hh] = s2;
      }
    }
  } else {
    int row = t >> 2, q = t & 3;
    int gr = row0 + row;
    uint4 u0 = *(const uint4*)(xs + row * 136 + q * 16);
    uint4 u1 = *(const uint4*)(xs + row * 136 + q * 16 + 8);
    float hv[16] = {bflo(u0.x), bfhi(u0.x), bflo(u0.y), bfhi(u0.y),
                    bflo(u0.z), bfhi(u0.z), bflo(u0.w), bfhi(u0.w),
                    bflo(u1.x), bfhi(u1.x), bflo(u1.y), bfhi(u1.y),
                    bflo(u1.z), bfhi(u1.z), bflo(u1.w), bfhi(u1.w)};
    float s1 = 0.f, s2 = 0.f;
#pragma unroll
    for (int j = 0; j < 16; ++j) { s1 += hv[j] * asl[q * 16 + j]; s2 += hv[j] * adl[q * 16 + j]; }
    s1 += __shfl_xor(s1, 1); s1 += __shfl_xor(s1, 2);
    s2 += __shfl_xor(s2, 1); s2 += __shfl_xor(s2, 2);
    if (gr < NN) {
      *(uint4*)(Hf + (size_t)gr * 64 + q * 16)     = u0;
      *(uint4*)(Hf + (size_t)gr * 64 + q * 16 + 8) = u1;
      if (q == 0) { as_[gr] = s1; ad_[gr] = s2; }
    }
  }
}

// ---------------- aggregation: single pass, inline exp, 4-way ILP, no LDS/barriers ----------------
template<int HH, int C, bool FINAL>
__global__ __launch_bounds__(256) void k_aggregate(const unsigned short* __restrict__ Hf,
                                                   const float* __restrict__ as_, const float* __restrict__ ad_,
                                                   const int* __restrict__ rowptr, const int* __restrict__ esrc,
                                                   const float* __restrict__ bias,
                                                   const float* __restrict__ Wout, const float* __restrict__ bout,
                                                   unsigned short* __restrict__ outb, float* __restrict__ outf) {
  constexpr int CT = HH * C;
  constexpr int Q = CT / 8;
  int g = blockIdx.x * 256 + threadIdx.x;
  if (g >= NN * Q) return;
  int node = g / Q;
  int q = g - node * Q;
  int c = q * 8;
  int hh = c / C;
  int i0 = rowptr[node], i1 = rowptr[node + 1];
  float ad = ad_[node * HH + hh];
  float d[4] = {0.f, 0.f, 0.f, 0.f};
  float a[4][8] = {};
  int i = i0;
  for (; i + 3 < i1; i += 4) {
    int sx[4]; float ex[4]; uint4 hx[4];
#pragma unroll
    for (int c4 = 0; c4 < 4; ++c4) sx[c4] = esrc[i + c4];
#pragma unroll
    for (int c4 = 0; c4 < 4; ++c4) ex[c4] = as_[sx[c4] * HH + hh] + ad;
#pragma unroll
    for (int c4 = 0; c4 < 4; ++c4) hx[c4] = *(const uint4*)(Hf + (size_t)sx[c4] * CT + c);
#pragma unroll
    for (int c4 = 0; c4 < 4; ++c4) {
      float e = fmaxf(ex[c4], 0.2f * ex[c4]);
      float pp = __expf(e);
      d[c4] += pp;
      a[c4][0] = fmaf(pp, bflo(hx[c4].x), a[c4][0]);
      a[c4][1] = fmaf(pp, bfhi(hx[c4].x), a[c4][1]);
      a[c4][2] = fmaf(pp, bflo(hx[c4].y), a[c4][2]);
      a[c4][3] = fmaf(pp, bfhi(hx[c4].y), a[c4][3]);
      a[c4][4] = fmaf(pp, bflo(hx[c4].z), a[c4][4]);
      a[c4][5] = fmaf(pp, bfhi(hx[c4].z), a[c4][5]);
      a[c4][6] = fmaf(pp, bflo(hx[c4].w), a[c4][6]);
      a[c4][7] = fmaf(pp, bfhi(hx[c4].w), a[c4][7]);
    }
  }
  for (; i < i1; ++i) {
    int s = esrc[i];
    float e = as_[s * HH + hh] + ad;
    uint4 h0 = *(const uint4*)(Hf + (size_t)s * CT + c);
    e = fmaxf(e, 0.2f * e);
    float pp = __expf(e);
    d[0] += pp;
    a[0][0] = fmaf(pp, bflo(h0.x), a[0][0]);
    a[0][1] = fmaf(pp, bfhi(h0.x), a[0][1]);
    a[0][2] = fmaf(pp, bflo(h0.y), a[0][2]);
    a[0][3] = fmaf(pp, bfhi(h0.y), a[0][3]);
    a[0][4] = fmaf(pp, bflo(h0.z), a[0][4]);
    a[0][5] = fmaf(pp, bfhi(h0.z), a[0][5]);
    a[0][6] = fmaf(pp, bflo(h0.w), a[0][6]);
    a[0][7] = fmaf(pp, bfhi(h0.w), a[0][7]);
  }
  float inv = 1.f / (d[0] + d[1] + d[2] + d[3]);
  float o[8];
#pragma unroll
  for (int j = 0; j < 8; ++j) {
    float v = (a[0][j] + a[1][j] + a[2][j] + a[3][j]) * inv + bias[c + j];
    o[j] = v > 0.f ? v : __expf(v) - 1.f;              // ELU
  }
  if constexpr (!FINAL) {
    uint4 pk;
    pk.x = (unsigned)f2bf(o[0]) | ((unsigned)f2bf(o[1]) << 16);
    pk.y = (unsigned)f2bf(o[2]) | ((unsigned)f2bf(o[3]) << 16);
    pk.z = (unsigned)f2bf(o[4]) | ((unsigned)f2bf(o[5]) << 16);
    pk.w = (unsigned)f2bf(o[6]) | ((unsigned)f2bf(o[7]) << 16);
    *(uint4*)(outb + (size_t)node * CT + c) = pk;
  } else {
    float p0 = 0.f, p1 = 0.f;
#pragma unroll
    for (int j = 0; j < 8; ++j) { p0 += o[j] * Wout[(c + j) * 2 + 0]; p1 += o[j] * Wout[(c + j) * 2 + 1]; }
#pragma unroll
    for (int off = 1; off < 8; off <<= 1) { p0 += __shfl_xor(p0, off); p1 += __shfl_xor(p1, off); }
    if (q == 0) { outf[node * 2 + 0] = p0 + bout[0]; outf[node * 2 + 1] = p1 + bout[1]; }
  }
}

extern "C" void kernel_launch(void* const* d_in, const int* in_sizes, int n_in,
                              void* d_out, int out_size, void* d_ws, size_t ws_size,
                              hipStream_t stream) {
  const float* x    = (const float*)d_in[0];
  const int*   ei   = (const int*)d_in[1];
  const float* W1   = (const float*)d_in[2];
  const float* as1  = (const float*)d_in[3];
  const float* ad1  = (const float*)d_in[4];
  const float* b1   = (const float*)d_in[5];
  const float* W2   = (const float*)d_in[6];
  const float* as2  = (const float*)d_in[7];
  const float* ad2  = (const float*)d_in[8];
  const float* b2   = (const float*)d_in[9];
  const float* W3   = (const float*)d_in[10];
  const float* as3  = (const float*)d_in[11];
  const float* ad3  = (const float*)d_in[12];
  const float* b3   = (const float*)d_in[13];
  const float* Wout = (const float*)d_in[14];
  const float* bout = (const float*)d_in[15];
  const int* srcp = ei;
  const int* dstp = ei + NE;

  char* p = (char*)d_ws;
  auto alloc = [&](size_t bytes) { char* r = p; p += (bytes + 255) & ~size_t(255); return r; };
  int*            rowptr  = (int*)alloc((size_t)(NN + 1) * 4);
  int*            counts  = (int*)alloc((size_t)NN * 4);
  int*            partial = (int*)alloc((size_t)NN * 4);
  int*            blksum  = (int*)alloc(256 * 4);
  int*            esrc    = (int*)alloc((size_t)ET * 4);
  int*            slots   = (int*)alloc((size_t)ET * 4);
  float*          asb     = (float*)alloc((size_t)NN * 8 * 4);
  float*          adb     = (float*)alloc((size_t)NN * 8 * 4);
  unsigned short* hfb     = (unsigned short*)alloc((size_t)NN * 128 * 2);   // bf16 gather table
  unsigned short* actb    = (unsigned short*)alloc((size_t)NN * 128 * 2);   // bf16 activations

  hipMemsetAsync(counts, 0, (size_t)NN * 4, stream);
  int gE16 = (ET + 4095) / 4096;
  int nb = (NN + SCAN_BLK - 1) / SCAN_BLK;
  k_hist<<<gE16, 256, 0, stream>>>(dstp, counts, slots);
  k_scan1<<<nb, 256, 0, stream>>>(counts, partial, blksum);
  k_scan2<<<1, 256, 0, stream>>>(blksum, nb);
  k_scan3<<<(NN + 255) / 256, 256, 0, stream>>>(partial, blksum, rowptr);
  k_scatter<<<gE16, 256, 0, stream>>>(srcp, dstp, rowptr, slots, esrc);

  int gGemm = (NN + 63) / 64;
  // layer 1: 128 -> 8x16, concat, ELU
  k_gemm<128, false><<<gGemm, 256, 0, stream>>>(x, nullptr, W1, as1, ad1, hfb, asb, adb);
  k_aggregate<8, 16, false><<<(NN * 16 + 255) / 256, 256, 0, stream>>>(hfb, asb, adb, rowptr, esrc, b1, nullptr, nullptr, actb, nullptr);
  // layer 2
  k_gemm<128, true><<<gGemm, 256, 0, stream>>>(nullptr, actb, W2, as2, ad2, hfb, asb, adb);
  k_aggregate<8, 16, false><<<(NN * 16 + 255) / 256, 256, 0, stream>>>(hfb, asb, adb, rowptr, esrc, b2, nullptr, nullptr, actb, nullptr);
  // layer 3: 128 -> 1x64, mean(=identity), ELU, fused 64->2 output linear
  k_gemm<64, true><<<gGemm, 256, 0, stream>>>(nullptr, actb, W3, as3, ad3, hfb, asb, adb);
  k_aggregate<1, 64, true><<<(NN * 8 + 255) / 256, 256, 0, stream>>>(hfb, asb, adb, rowptr, esrc, b3, Wout, bout, nullptr, (float*)d_out);
}